// Round 6
// baseline (294.737 us; speedup 1.0000x reference)
//
#include <hip/hip_runtime.h>
#include <hip/hip_bf16.h>
#include <math.h>

// Problem constants: B=8, S=1024, D=768, H=12, DH=64. fp32 in, fp32 out.
constexpr int Bn = 8, Sn = 1024, Dn = 768, Hn = 12, DHn = 64;
constexpr int QKV_ELEMS = Bn * Hn * Sn * DHn;  // 6291456
// sqrt(log2(e)/sqrt(DH)) — folded into Wq,bq,Wk,bk so scores come out
// pre-scaled for exp2. 0.42466086^2 = 0.18033688 = 0.125*log2(e).
constexpr float SQC = 0.42466086f;

typedef __attribute__((ext_vector_type(8))) short bf16x8;  // 8 bf16 = 4 VGPRs
typedef __attribute__((ext_vector_type(4))) float f32x4;   // MFMA 16x16 C/D

__device__ __forceinline__ unsigned short f2bf(float f) {   // RNE, no NaN path
    union { float f; unsigned u; } c{f};
    return (unsigned short)((c.u + 0x7FFF + ((c.u >> 16) & 1)) >> 16);
}
__device__ __forceinline__ unsigned int pk2bf(float a, float b) {  // pack 2
    union { float f; unsigned u; } ca{a}, cb{b};
    unsigned ra = (ca.u + 0x7FFF + ((ca.u >> 16) & 1)) >> 16;
    unsigned rb = (cb.u + 0x7FFF + ((cb.u >> 16) & 1)) & 0xFFFF0000u;
    return ra | rb;
}

// ---------------------------------------------------------------------------
// Kernel 0 (prep): W^T -> bf16, once. wt_g[(m*12+h)*64 + e][d], m in {q,k,v}.
// Wq,Wk scaled by SQC (softmax scale folded). 36 blocks.
// ---------------------------------------------------------------------------
__global__ __launch_bounds__(256) void prep_kernel(
    const float* __restrict__ Wq, const float* __restrict__ Wk,
    const float* __restrict__ Wv, unsigned short* __restrict__ wt_g)
{
    __shared__ float Ws[64][65];
    const int mh = blockIdx.x;          // m*12 + h
    const int m  = mh / Hn;
    const int h  = mh % Hn;
    const float* W = (m == 0 ? Wq : (m == 1 ? Wk : Wv)) + (size_t)h * 4096;
    const int t  = threadIdx.x;
    const int r  = t >> 2;              // d row
    const int c0 = (t & 3) * 16;        // e col base
    #pragma unroll
    for (int q4 = 0; q4 < 4; q4++) {
        float4 v = ((const float4*)(W + r * 64 + c0))[q4];
        Ws[r][c0 + 4 * q4 + 0] = v.x;
        Ws[r][c0 + 4 * q4 + 1] = v.y;
        Ws[r][c0 + 4 * q4 + 2] = v.z;
        Ws[r][c0 + 4 * q4 + 3] = v.w;
    }
    __syncthreads();
    const int e  = t >> 2;
    const int d0 = (t & 3) * 16;
    const float sc = (m < 2) ? SQC : 1.0f;
    unsigned short tmp[16];
    #pragma unroll
    for (int j = 0; j < 16; j++) tmp[j] = f2bf(Ws[d0 + j][e] * sc);
    uint4* dst = (uint4*)(wt_g + ((size_t)(mh * 64 + e)) * 64 + d0);
    dst[0] = ((uint4*)tmp)[0];
    dst[1] = ((uint4*)tmp)[1];
}

// ---------------------------------------------------------------------------
// Kernel 1 (proj): all three projections as D[e][s] = W^T . X^T per wave
// e-strip. A = wt_g rows (global, L2-hot, coalesced dwordx4); B = X s-tiles
// (LDS). q,k written packed b64 to [bh][s][64]; v written transposed to
// vt_ws [bh][dh][S] (scalar b16, 32B segments).
// ---------------------------------------------------------------------------
__global__ __launch_bounds__(256) void proj_kernel(
    const float* __restrict__ x, const unsigned short* __restrict__ wt_g,
    const float* __restrict__ bq, const float* __restrict__ bk,
    const float* __restrict__ bv,
    unsigned short* __restrict__ q_ws, unsigned short* __restrict__ k_ws,
    unsigned short* __restrict__ vt_ws)
{
    __shared__ unsigned short Xs[64 * 72];   // [s][d] bf16, 2-way banks (free)

    const int blk  = blockIdx.x;        // (b*H + h)*16 + tile
    const int tile = blk & 15;
    const int bh   = blk >> 4;
    const int h    = bh % Hn;
    const int b    = bh / Hn;
    const int t    = threadIdx.x;
    const int w    = t >> 6;            // wave 0..3 -> e-strip w*16
    const int lane = t & 63;
    const int l    = lane & 15;
    const int quad = lane >> 4;
    const int r    = t >> 2;            // staging row
    const int c0   = (t & 3) * 16;      // staging col base
    const int s0   = tile * 64;

    {   // stage X tile [64 s][64 d] fp32 -> bf16
        const float* xrow = x + ((size_t)(b * Sn + s0 + r) * Dn + h * 64 + c0);
        unsigned int tmp[8];
        #pragma unroll
        for (int q4 = 0; q4 < 4; q4++) {
            float4 v = ((const float4*)xrow)[q4];
            tmp[2 * q4 + 0] = pk2bf(v.x, v.y);
            tmp[2 * q4 + 1] = pk2bf(v.z, v.w);
        }
        *(uint4*)&Xs[r * 72 + c0]     = ((uint4*)tmp)[0];
        *(uint4*)&Xs[r * 72 + c0 + 8] = ((uint4*)tmp)[1];
    }
    __syncthreads();

    // B fragments: X s-tiles (shared by q,k,v)
    bf16x8 xb[4][2];
    #pragma unroll
    for (int nt = 0; nt < 4; nt++)
        #pragma unroll
        for (int kc = 0; kc < 2; kc++)
            xb[nt][kc] = *(bf16x8*)&Xs[(nt * 16 + l) * 72 + kc * 32 + quad * 8];

    const float* bias_m[3] = {bq, bk, bv};
    #pragma unroll
    for (int m = 0; m < 3; m++) {
        // A fragments: W^T rows e = w*16 + l, straight from global
        const unsigned short* wp = wt_g + ((size_t)((m * Hn + h) * 64 + w * 16 + l)) * 64 + quad * 8;
        uint4 wa0 = *(const uint4*)wp;
        uint4 wa1 = *(const uint4*)(wp + 32);
        bf16x8 wa[2] = {*(bf16x8*)&wa0, *(bf16x8*)&wa1};

        const float* bb = bias_m[m] + h * 64 + w * 16 + quad * 4;
        const float bsc = (m < 2) ? SQC : 1.0f;
        f32x4 binit = (f32x4){bb[0] * bsc, bb[1] * bsc, bb[2] * bsc, bb[3] * bsc};
        f32x4 acc[4];
        #pragma unroll
        for (int nt = 0; nt < 4; nt++) acc[nt] = binit;
        #pragma unroll
        for (int nt = 0; nt < 4; nt++)
            #pragma unroll
            for (int kc = 0; kc < 2; kc++)
                acc[nt] = __builtin_amdgcn_mfma_f32_16x16x32_bf16(wa[kc], xb[nt][kc], acc[nt], 0, 0, 0);

        if (m < 2) {   // q,k: [bh][s][e] packed b64 (4 consecutive e)
            unsigned short* o = (m == 0 ? q_ws : k_ws);
            #pragma unroll
            for (int nt = 0; nt < 4; nt++) {
                uint2 pw = make_uint2(pk2bf(acc[nt][0], acc[nt][1]),
                                      pk2bf(acc[nt][2], acc[nt][3]));
                *(uint2*)(o + (size_t)(bh * Sn + s0 + nt * 16 + l) * 64 + w * 16 + quad * 4) = pw;
            }
        } else {       // v: transposed [bh][e][S]
            unsigned short* vt = vt_ws + (size_t)bh * 64 * Sn;
            #pragma unroll
            for (int nt = 0; nt < 4; nt++)
                #pragma unroll
                for (int rr = 0; rr < 4; rr++)
                    vt[(size_t)(w * 16 + quad * 4 + rr) * Sn + s0 + nt * 16 + l] = f2bf(acc[nt][rr]);
        }
    }
}

// ---------------------------------------------------------------------------
// Kernel 2 (attn): barrier-free MFMA flash attention. Wave w owns 16 queries.
// S^T = K.Q^T (lane holds 4 consecutive keys x 1 query) -> exp2 (no max
// subtraction: scores statically bounded, scale pre-folded) -> P via b64 LDS
// roundtrip to A-layout -> O += P.V with V^T fragments from global.
// K/V fragments read directly from global (coalesced dwordx4, L1/L2-hot).
// Row-sum deferred to a single post-loop shuffle reduction.
// ---------------------------------------------------------------------------
__global__ __launch_bounds__(256) void attn_kernel(
    const unsigned short* __restrict__ q_ws,
    const unsigned short* __restrict__ k_ws,
    const unsigned short* __restrict__ vt_ws,
    float* __restrict__ out)
{
    __shared__ unsigned short Pws[4 * 16 * 72];  // per-wave P [query][key]

    const int blk  = blockIdx.x;   // (b*H+h)*16 + qt
    const int qt   = blk & 15;
    const int bh   = blk >> 4;
    const int t    = threadIdx.x;
    const int w    = t >> 6;
    const int lane = t & 63;
    const int l    = lane & 15;
    const int quad = lane >> 4;

    const size_t base  = (size_t)bh * Sn * 64;   // q/k [bh][s][64]
    const size_t vbase = (size_t)bh * 64 * Sn;   // vt  [bh][dh][S]

    // Q as B-fragment: B[k=d][n=query=l] = Q[query][d] (pre-scaled by SQC)
    bf16x8 qf[2];
    {
        const unsigned short* qp = q_ws + base + (size_t)(qt * 64 + w * 16 + l) * 64 + quad * 8;
        uint4 a = *(const uint4*)qp;
        uint4 b = *(const uint4*)(qp + 32);
        qf[0] = *(bf16x8*)&a;
        qf[1] = *(bf16x8*)&b;
    }

    f32x4 Oa[4];
    #pragma unroll
    for (int nt = 0; nt < 4; nt++) Oa[nt] = (f32x4){0.f, 0.f, 0.f, 0.f};
    float ps = 0.f;

    unsigned short* Pw = Pws + w * 16 * 72;

    for (int kt = 0; kt < 16; kt++) {
        // S^T tiles: A = K rows (global), B = qf
        f32x4 s[4];
        #pragma unroll
        for (int nt = 0; nt < 4; nt++) {
            const unsigned short* kp = k_ws + base + (size_t)(kt * 64 + nt * 16 + l) * 64 + quad * 8;
            uint4 k0 = *(const uint4*)kp;
            uint4 k1 = *(const uint4*)(kp + 32);
            s[nt] = (f32x4){0.f, 0.f, 0.f, 0.f};
            s[nt] = __builtin_amdgcn_mfma_f32_16x16x32_bf16(*(bf16x8*)&k0, qf[0], s[nt], 0, 0, 0);
            s[nt] = __builtin_amdgcn_mfma_f32_16x16x32_bf16(*(bf16x8*)&k1, qf[1], s[nt], 0, 0, 0);
        }

        // p = exp2(s'); accumulate l; publish P[query l][key] as packed b64
        #pragma unroll
        for (int nt = 0; nt < 4; nt++) {
            float p0 = exp2f(s[nt][0]), p1 = exp2f(s[nt][1]);
            float p2 = exp2f(s[nt][2]), p3 = exp2f(s[nt][3]);
            ps += (p0 + p1) + (p2 + p3);
            *(uint2*)&Pw[l * 72 + nt * 16 + quad * 4] =
                make_uint2(pk2bf(p0, p1), pk2bf(p2, p3));
        }
        __asm__ volatile("s_waitcnt lgkmcnt(0)" ::: "memory");

        bf16x8 pf[2];
        pf[0] = *(bf16x8*)&Pw[l * 72 + quad * 8];
        pf[1] = *(bf16x8*)&Pw[l * 72 + 32 + quad * 8];

        // O += P.V : B = V^T rows (global)
        #pragma unroll
        for (int nt = 0; nt < 4; nt++) {
            const unsigned short* vp = vt_ws + vbase + (size_t)(nt * 16 + l) * Sn + kt * 64 + quad * 8;
            uint4 v0 = *(const uint4*)vp;
            uint4 v1 = *(const uint4*)(vp + 32);
            Oa[nt] = __builtin_amdgcn_mfma_f32_16x16x32_bf16(pf[0], *(bf16x8*)&v0, Oa[nt], 0, 0, 0);
            Oa[nt] = __builtin_amdgcn_mfma_f32_16x16x32_bf16(pf[1], *(bf16x8*)&v1, Oa[nt], 0, 0, 0);
        }
    }

    // fold partial sums: quads of same query-column, then fetch per-row inv
    ps += __shfl_xor(ps, 16, 64);
    ps += __shfl_xor(ps, 32, 64);
    float inv[4];
    #pragma unroll
    for (int r = 0; r < 4; r++) inv[r] = 1.0f / __shfl(ps, quad * 4 + r, 64);

    const int b = bh / Hn, h = bh % Hn;
    #pragma unroll
    for (int nt = 0; nt < 4; nt++)
        #pragma unroll
        for (int r = 0; r < 4; r++) {
            int srow = qt * 64 + w * 16 + quad * 4 + r;
            out[(size_t)(b * Sn + srow) * Dn + h * 64 + nt * 16 + l] = Oa[nt][r] * inv[r];
        }
}

// ---------------------------------------------------------------------------
extern "C" void kernel_launch(void* const* d_in, const int* in_sizes, int n_in,
                              void* d_out, int out_size, void* d_ws, size_t ws_size,
                              hipStream_t stream) {
    const float* x  = (const float*)d_in[0];
    const float* Wq = (const float*)d_in[1];
    const float* bq = (const float*)d_in[2];
    const float* Wk = (const float*)d_in[3];
    const float* bk = (const float*)d_in[4];
    const float* Wv = (const float*)d_in[5];
    const float* bv = (const float*)d_in[6];
    float* out = (float*)d_out;

    unsigned short* q_ws  = (unsigned short*)d_ws;
    unsigned short* k_ws  = q_ws + QKV_ELEMS;
    unsigned short* vt_ws = k_ws + QKV_ELEMS;
    unsigned short* wt_g  = vt_ws + QKV_ELEMS;   // 36*64*64 bf16 = 288 KB

    hipLaunchKernelGGL(prep_kernel, dim3(3 * Hn), dim3(256), 0, stream,
                       Wq, Wk, Wv, wt_g);
    hipLaunchKernelGGL(proj_kernel, dim3(Bn * Hn * 16), dim3(256), 0, stream,
                       x, wt_g, bq, bk, bv, q_ws, k_ws, vt_ws);
    hipLaunchKernelGGL(attn_kernel, dim3(Bn * Hn * 16), dim3(256), 0, stream,
                       q_ws, k_ws, vt_ws, out);
}

// Round 7
// 149.378 us; speedup vs baseline: 1.9731x; 1.9731x over previous
//
#include <hip/hip_runtime.h>
#include <hip/hip_bf16.h>
#include <math.h>

// Problem constants: B=8, S=1024, D=768, H=12, DH=64. fp32 in, fp32 out.
constexpr int Bn = 8, Sn = 1024, Dn = 768, Hn = 12, DHn = 64;
constexpr int QKV_ELEMS = Bn * Hn * Sn * DHn;  // 6291456
// sqrt(log2(e)/sqrt(DH)) — folded into Wq,bq,Wk,bk so scores come out
// pre-scaled for exp2. 0.42466086^2 = 0.18033688 = 0.125*log2(e).
constexpr float SQC = 0.42466086f;

typedef __attribute__((ext_vector_type(8))) short bf16x8;  // 8 bf16 = 4 VGPRs
typedef __attribute__((ext_vector_type(4))) float f32x4;   // MFMA 16x16 C/D

__device__ __forceinline__ unsigned short f2bf(float f) {   // RNE, no NaN path
    union { float f; unsigned u; } c{f};
    return (unsigned short)((c.u + 0x7FFF + ((c.u >> 16) & 1)) >> 16);
}
__device__ __forceinline__ unsigned int pk2bf(float a, float b) {  // pack 2
    union { float f; unsigned u; } ca{a}, cb{b};
    unsigned ra = (ca.u + 0x7FFF + ((ca.u >> 16) & 1)) >> 16;
    unsigned rb = (cb.u + 0x7FFF + ((cb.u >> 16) & 1)) & 0xFFFF0000u;
    return ra | rb;
}

// ---------------------------------------------------------------------------
// Kernel 0 (prep): W^T -> bf16, once. wt_g[(m*12+h)*64 + e][d], m in {q,k,v}.
// Wq,Wk scaled by SQC (softmax scale folded). 36 blocks.
// ---------------------------------------------------------------------------
__global__ __launch_bounds__(256) void prep_kernel(
    const float* __restrict__ Wq, const float* __restrict__ Wk,
    const float* __restrict__ Wv, unsigned short* __restrict__ wt_g)
{
    __shared__ float Ws[64][65];
    const int mh = blockIdx.x;          // m*12 + h
    const int m  = mh / Hn;
    const int h  = mh % Hn;
    const float* W = (m == 0 ? Wq : (m == 1 ? Wk : Wv)) + (size_t)h * 4096;
    const int t  = threadIdx.x;
    const int r  = t >> 2;              // d row
    const int c0 = (t & 3) * 16;        // e col base
    #pragma unroll
    for (int q4 = 0; q4 < 4; q4++) {
        float4 v = ((const float4*)(W + r * 64 + c0))[q4];
        Ws[r][c0 + 4 * q4 + 0] = v.x;
        Ws[r][c0 + 4 * q4 + 1] = v.y;
        Ws[r][c0 + 4 * q4 + 2] = v.z;
        Ws[r][c0 + 4 * q4 + 3] = v.w;
    }
    __syncthreads();
    const int e  = t >> 2;
    const int d0 = (t & 3) * 16;
    const float sc = (m < 2) ? SQC : 1.0f;
    unsigned short tmp[16];
    #pragma unroll
    for (int j = 0; j < 16; j++) tmp[j] = f2bf(Ws[d0 + j][e] * sc);
    uint4* dst = (uint4*)(wt_g + ((size_t)(mh * 64 + e)) * 64 + d0);
    dst[0] = ((uint4*)tmp)[0];
    dst[1] = ((uint4*)tmp)[1];
}

// ---------------------------------------------------------------------------
// Kernel 1 (proj): D[e][s] = W^T . X^T per wave e-strip; A = wt_g rows
// (global, L2-hot), B = X s-tiles (LDS). Results routed THROUGH LDS so all
// global stores are coalesced b128: q,k as [bh][s][64]; v as [bh][dh][S].
// ---------------------------------------------------------------------------
__global__ __launch_bounds__(256) void proj_kernel(
    const float* __restrict__ x, const unsigned short* __restrict__ wt_g,
    const float* __restrict__ bq, const float* __restrict__ bk,
    const float* __restrict__ bv,
    unsigned short* __restrict__ q_ws, unsigned short* __restrict__ k_ws,
    unsigned short* __restrict__ vt_ws)
{
    __shared__ unsigned short Xs[64 * 72];   // [s][d] bf16
    __shared__ unsigned short Ob[64 * 72];   // output staging (q,k: [s][e]; v: [e][s])

    const int blk  = blockIdx.x;        // (b*H + h)*16 + tile
    const int tile = blk & 15;
    const int bh   = blk >> 4;
    const int h    = bh % Hn;
    const int b    = bh / Hn;
    const int t    = threadIdx.x;
    const int w    = t >> 6;            // wave 0..3 -> e-strip w*16
    const int lane = t & 63;
    const int l    = lane & 15;
    const int quad = lane >> 4;
    const int r    = t >> 2;            // staging row
    const int c0   = (t & 3) * 16;      // staging col base
    const int s0   = tile * 64;

    {   // stage X tile [64 s][64 d] fp32 -> bf16
        const float* xrow = x + ((size_t)(b * Sn + s0 + r) * Dn + h * 64 + c0);
        unsigned int tmp[8];
        #pragma unroll
        for (int q4 = 0; q4 < 4; q4++) {
            float4 v = ((const float4*)xrow)[q4];
            tmp[2 * q4 + 0] = pk2bf(v.x, v.y);
            tmp[2 * q4 + 1] = pk2bf(v.z, v.w);
        }
        *(uint4*)&Xs[r * 72 + c0]     = ((uint4*)tmp)[0];
        *(uint4*)&Xs[r * 72 + c0 + 8] = ((uint4*)tmp)[1];
    }
    __syncthreads();

    // B fragments: X s-tiles (shared by q,k,v)
    bf16x8 xb[4][2];
    #pragma unroll
    for (int nt = 0; nt < 4; nt++)
        #pragma unroll
        for (int kc = 0; kc < 2; kc++)
            xb[nt][kc] = *(bf16x8*)&Xs[(nt * 16 + l) * 72 + kc * 32 + quad * 8];

    const float* bias_m[3] = {bq, bk, bv};
    #pragma unroll
    for (int m = 0; m < 3; m++) {
        // A fragments: W^T rows e = w*16 + l (global, L2-hot)
        const unsigned short* wp = wt_g + ((size_t)((m * Hn + h) * 64 + w * 16 + l)) * 64 + quad * 8;
        uint4 wa0 = *(const uint4*)wp;
        uint4 wa1 = *(const uint4*)(wp + 32);
        bf16x8 wa[2] = {*(bf16x8*)&wa0, *(bf16x8*)&wa1};

        const float* bb = bias_m[m] + h * 64 + w * 16 + quad * 4;
        const float bsc = (m < 2) ? SQC : 1.0f;
        f32x4 binit = (f32x4){bb[0] * bsc, bb[1] * bsc, bb[2] * bsc, bb[3] * bsc};
        f32x4 acc[4];
        #pragma unroll
        for (int nt = 0; nt < 4; nt++) acc[nt] = binit;
        #pragma unroll
        for (int nt = 0; nt < 4; nt++)
            #pragma unroll
            for (int kc = 0; kc < 2; kc++)
                acc[nt] = __builtin_amdgcn_mfma_f32_16x16x32_bf16(wa[kc], xb[nt][kc], acc[nt], 0, 0, 0);

        __syncthreads();   // Ob free (prev m readers done)
        if (m < 2) {       // Ob[s][e]: packed b64 (4 consecutive e)
            #pragma unroll
            for (int nt = 0; nt < 4; nt++)
                *(uint2*)&Ob[(nt * 16 + l) * 72 + w * 16 + quad * 4] =
                    make_uint2(pk2bf(acc[nt][0], acc[nt][1]),
                               pk2bf(acc[nt][2], acc[nt][3]));
        } else {           // Ob[e][s]: b16 scatter (cheap in LDS)
            #pragma unroll
            for (int nt = 0; nt < 4; nt++)
                #pragma unroll
                for (int rr = 0; rr < 4; rr++)
                    Ob[(w * 16 + quad * 4 + rr) * 72 + nt * 16 + l] = f2bf(acc[nt][rr]);
        }
        __syncthreads();

        // coalesced b128 global stores
        uint4 oa = *(uint4*)&Ob[r * 72 + c0];
        uint4 ob2 = *(uint4*)&Ob[r * 72 + c0 + 8];
        unsigned short* dst;
        if (m == 0)      dst = q_ws  + (size_t)(bh * Sn + s0 + r) * 64 + c0;
        else if (m == 1) dst = k_ws  + (size_t)(bh * Sn + s0 + r) * 64 + c0;
        else             dst = vt_ws + (size_t)bh * 64 * Sn + (size_t)r * Sn + s0 + c0;
        ((uint4*)dst)[0] = oa;
        *(uint4*)(dst + 8) = ob2;
    }
}

// ---------------------------------------------------------------------------
// Kernel 2 (attn): MFMA flash attention, 128 queries/block (32/wave, 2 strips)
// with block-level K/V LDS staging. S^T = K.Q^T -> exp2 (no max: scores
// statically bounded, scale pre-folded) -> packed-b64 P roundtrip per wave ->
// O += P.V. XCD swizzle: 12 bh x 8 q-blocks per XCD -> K/V L2-resident.
// Row-sum deferred to post-loop shuffles.
// ---------------------------------------------------------------------------
__global__ __launch_bounds__(256) void attn_kernel(
    const unsigned short* __restrict__ q_ws,
    const unsigned short* __restrict__ k_ws,
    const unsigned short* __restrict__ vt_ws,
    float* __restrict__ out)
{
    __shared__ unsigned short Ks[64 * 72];       // [key][dh]
    __shared__ unsigned short Vt[64 * 72];       // [dh][key]
    __shared__ unsigned short Pws[4 * 32 * 72];  // per-wave P [query][key]

    const int blk = blockIdx.x;    // 768 = 8 XCD * 12 bh * 8 qt
    const int xcd = blk & 7;
    const int idx = blk >> 3;      // 0..95
    const int bh  = xcd * 12 + (idx % 12);
    const int qt  = idx / 12;      // 0..7 (128-query tiles)
    const int t    = threadIdx.x;
    const int w    = t >> 6;
    const int lane = t & 63;
    const int l    = lane & 15;
    const int quad = lane >> 4;
    const int sr   = t >> 2;
    const int sc0  = (t & 3) * 16;

    const size_t base  = (size_t)bh * Sn * 64;   // q/k [bh][s][64]
    const size_t vbase = (size_t)bh * 64 * Sn;   // vt  [bh][dh][S]

    // Q as B-fragments, 2 strips of 16 queries
    bf16x8 qf[2][2];
    #pragma unroll
    for (int st = 0; st < 2; st++) {
        const unsigned short* qp = q_ws + base +
            (size_t)(qt * 128 + w * 32 + st * 16 + l) * 64 + quad * 8;
        uint4 a = *(const uint4*)qp;
        uint4 b = *(const uint4*)(qp + 32);
        qf[st][0] = *(bf16x8*)&a;
        qf[st][1] = *(bf16x8*)&b;
    }

    f32x4 Oa[2][4];
    #pragma unroll
    for (int st = 0; st < 2; st++)
        #pragma unroll
        for (int nt = 0; nt < 4; nt++) Oa[st][nt] = (f32x4){0.f, 0.f, 0.f, 0.f};
    float ps[2] = {0.f, 0.f};

    unsigned short* Pw = Pws + w * 32 * 72;

    for (int kt = 0; kt < 16; kt++) {
        __syncthreads();   // drain prev-iter Ks/Vt readers
        {   // stage K tile [key][dh] and V^T tile [dh][key]
            const unsigned short* kp = k_ws + base + (size_t)(kt * 64 + sr) * 64 + sc0;
            uint4 ka = *(const uint4*)kp;
            uint4 kb = *(const uint4*)(kp + 8);
            const unsigned short* vp = vt_ws + vbase + (size_t)sr * Sn + kt * 64 + sc0;
            uint4 va = *(const uint4*)vp;
            uint4 vb = *(const uint4*)(vp + 8);
            *(uint4*)&Ks[sr * 72 + sc0]     = ka;
            *(uint4*)&Ks[sr * 72 + sc0 + 8] = kb;
            *(uint4*)&Vt[sr * 72 + sc0]     = va;
            *(uint4*)&Vt[sr * 72 + sc0 + 8] = vb;
        }
        __syncthreads();

        // S^T per key-strip nt: A = K rows, B = Q; then exp2 + packed P write
        #pragma unroll
        for (int nt = 0; nt < 4; nt++) {
            bf16x8 kf0 = *(bf16x8*)&Ks[(nt * 16 + l) * 72 + quad * 8];
            bf16x8 kf1 = *(bf16x8*)&Ks[(nt * 16 + l) * 72 + 32 + quad * 8];
            #pragma unroll
            for (int st = 0; st < 2; st++) {
                f32x4 s = (f32x4){0.f, 0.f, 0.f, 0.f};
                s = __builtin_amdgcn_mfma_f32_16x16x32_bf16(kf0, qf[st][0], s, 0, 0, 0);
                s = __builtin_amdgcn_mfma_f32_16x16x32_bf16(kf1, qf[st][1], s, 0, 0, 0);
                float p0 = exp2f(s[0]), p1 = exp2f(s[1]);
                float p2 = exp2f(s[2]), p3 = exp2f(s[3]);
                ps[st] += (p0 + p1) + (p2 + p3);
                *(uint2*)&Pw[(st * 16 + l) * 72 + nt * 16 + quad * 4] =
                    make_uint2(pk2bf(p0, p1), pk2bf(p2, p3));
            }
        }
        __asm__ volatile("s_waitcnt lgkmcnt(0)" ::: "memory");

        bf16x8 pf[2][2];
        #pragma unroll
        for (int st = 0; st < 2; st++) {
            pf[st][0] = *(bf16x8*)&Pw[(st * 16 + l) * 72 + quad * 8];
            pf[st][1] = *(bf16x8*)&Pw[(st * 16 + l) * 72 + 32 + quad * 8];
        }

        // O += P.V : B = V^T rows from LDS, shared across strips
        #pragma unroll
        for (int nt = 0; nt < 4; nt++) {
            bf16x8 vf0 = *(bf16x8*)&Vt[(nt * 16 + l) * 72 + quad * 8];
            bf16x8 vf1 = *(bf16x8*)&Vt[(nt * 16 + l) * 72 + 32 + quad * 8];
            #pragma unroll
            for (int st = 0; st < 2; st++) {
                Oa[st][nt] = __builtin_amdgcn_mfma_f32_16x16x32_bf16(pf[st][0], vf0, Oa[st][nt], 0, 0, 0);
                Oa[st][nt] = __builtin_amdgcn_mfma_f32_16x16x32_bf16(pf[st][1], vf1, Oa[st][nt], 0, 0, 0);
            }
        }
    }

    // fold partial sums across the 4 quads (keys), then fetch per-query inv
    #pragma unroll
    for (int st = 0; st < 2; st++) {
        ps[st] += __shfl_xor(ps[st], 16, 64);
        ps[st] += __shfl_xor(ps[st], 32, 64);
    }

    const int b = bh / Hn, h = bh % Hn;
    #pragma unroll
    for (int st = 0; st < 2; st++) {
        float inv[4];
        #pragma unroll
        for (int r = 0; r < 4; r++) inv[r] = 1.0f / __shfl(ps[st], quad * 4 + r, 64);
        #pragma unroll
        for (int nt = 0; nt < 4; nt++)
            #pragma unroll
            for (int r = 0; r < 4; r++) {
                int srow = qt * 128 + w * 32 + st * 16 + quad * 4 + r;
                out[(size_t)(b * Sn + srow) * Dn + h * 64 + nt * 16 + l] = Oa[st][nt][r] * inv[r];
            }
    }
}

// ---------------------------------------------------------------------------
extern "C" void kernel_launch(void* const* d_in, const int* in_sizes, int n_in,
                              void* d_out, int out_size, void* d_ws, size_t ws_size,
                              hipStream_t stream) {
    const float* x  = (const float*)d_in[0];
    const float* Wq = (const float*)d_in[1];
    const float* bq = (const float*)d_in[2];
    const float* Wk = (const float*)d_in[3];
    const float* bk = (const float*)d_in[4];
    const float* Wv = (const float*)d_in[5];
    const float* bv = (const float*)d_in[6];
    float* out = (float*)d_out;

    unsigned short* q_ws  = (unsigned short*)d_ws;
    unsigned short* k_ws  = q_ws + QKV_ELEMS;
    unsigned short* vt_ws = k_ws + QKV_ELEMS;
    unsigned short* wt_g  = vt_ws + QKV_ELEMS;   // 36*64*64 bf16 = 288 KB

    hipLaunchKernelGGL(prep_kernel, dim3(3 * Hn), dim3(256), 0, stream,
                       Wq, Wk, Wv, wt_g);
    hipLaunchKernelGGL(proj_kernel, dim3(Bn * Hn * 16), dim3(256), 0, stream,
                       x, wt_g, bq, bk, bv, q_ws, k_ws, vt_ws);
    hipLaunchKernelGGL(attn_kernel, dim3(Bn * Hn * 8), dim3(256), 0, stream,
                       q_ws, k_ws, vt_ws, out);
}

// Round 8
// 143.640 us; speedup vs baseline: 2.0519x; 1.0399x over previous
//
#include <hip/hip_runtime.h>
#include <hip/hip_bf16.h>
#include <math.h>

// Problem constants: B=8, S=1024, D=768, H=12, DH=64. fp32 in, fp32 out.
constexpr int Bn = 8, Sn = 1024, Dn = 768, Hn = 12, DHn = 64;
constexpr int QKV_ELEMS = Bn * Hn * Sn * DHn;  // 6291456
// sqrt(log2(e)/sqrt(DH)) — folded into Wq,bq,Wk,bk so scores come out
// pre-scaled for exp2. 0.42466086^2 = 0.18033688 = 0.125*log2(e).
constexpr float SQC = 0.42466086f;

typedef __attribute__((ext_vector_type(8))) short bf16x8;  // 8 bf16 = 4 VGPRs
typedef __attribute__((ext_vector_type(4))) float f32x4;   // MFMA 16x16 C/D

__device__ __forceinline__ unsigned short f2bf(float f) {   // RNE-ish, finite only
    union { float f; unsigned u; } c{f};
    return (unsigned short)((c.u + 0x8000) >> 16);
}
// pack 2 floats -> 2 bf16 (round-nearest) in 3 VALU ops: add, add, perm
__device__ __forceinline__ unsigned int pk2bf(float a, float b) {
    union { float f; unsigned u; } ca{a}, cb{b};
    return __builtin_amdgcn_perm(cb.u + 0x8000u, ca.u + 0x8000u, 0x07060302u);
}

// ---------------------------------------------------------------------------
// Kernel 0 (prep): W^T -> bf16, once. wt_g[(m*12+h)*64 + e][d], m in {q,k,v}.
// Wq,Wk scaled by SQC (softmax scale folded). 36 blocks.
// ---------------------------------------------------------------------------
__global__ __launch_bounds__(256) void prep_kernel(
    const float* __restrict__ Wq, const float* __restrict__ Wk,
    const float* __restrict__ Wv, unsigned short* __restrict__ wt_g)
{
    __shared__ float Ws[64][65];
    const int mh = blockIdx.x;          // m*12 + h
    const int m  = mh / Hn;
    const int h  = mh % Hn;
    const float* W = (m == 0 ? Wq : (m == 1 ? Wk : Wv)) + (size_t)h * 4096;
    const int t  = threadIdx.x;
    const int r  = t >> 2;              // d row
    const int c0 = (t & 3) * 16;        // e col base
    #pragma unroll
    for (int q4 = 0; q4 < 4; q4++) {
        float4 v = ((const float4*)(W + r * 64 + c0))[q4];
        Ws[r][c0 + 4 * q4 + 0] = v.x;
        Ws[r][c0 + 4 * q4 + 1] = v.y;
        Ws[r][c0 + 4 * q4 + 2] = v.z;
        Ws[r][c0 + 4 * q4 + 3] = v.w;
    }
    __syncthreads();
    const int e  = t >> 2;
    const int d0 = (t & 3) * 16;
    const float sc = (m < 2) ? SQC : 1.0f;
    unsigned short tmp[16];
    #pragma unroll
    for (int j = 0; j < 16; j++) tmp[j] = f2bf(Ws[d0 + j][e] * sc);
    uint4* dst = (uint4*)(wt_g + ((size_t)(mh * 64 + e)) * 64 + d0);
    dst[0] = ((uint4*)tmp)[0];
    dst[1] = ((uint4*)tmp)[1];
}

// ---------------------------------------------------------------------------
// Kernel 1 (proj): K and V only (Q is fused into attn). Single compute pass:
// D[e][s] = W^T . X^T for both matrices (16 MFMAs of ILP), then one sync,
// stage k as [s][e] (packed b64) + v as [e][s] in LDS, sync, b128 stores.
// ---------------------------------------------------------------------------
__global__ __launch_bounds__(256) void proj_kernel(
    const float* __restrict__ x, const unsigned short* __restrict__ wt_g,
    const float* __restrict__ bk, const float* __restrict__ bv,
    unsigned short* __restrict__ k_ws, unsigned short* __restrict__ vt_ws)
{
    __shared__ unsigned short Xs[64 * 72];   // [s][d] bf16
    __shared__ unsigned short ObK[64 * 72];  // [s][e]
    __shared__ unsigned short ObV[64 * 72];  // [e][s]

    const int blk  = blockIdx.x;        // (b*H + h)*16 + tile
    const int tile = blk & 15;
    const int bh   = blk >> 4;
    const int h    = bh % Hn;
    const int b    = bh / Hn;
    const int t    = threadIdx.x;
    const int w    = t >> 6;            // wave 0..3 -> e-strip w*16
    const int lane = t & 63;
    const int l    = lane & 15;
    const int quad = lane >> 4;
    const int r    = t >> 2;            // staging row
    const int c0   = (t & 3) * 16;      // staging col base
    const int s0   = tile * 64;

    {   // stage X tile [64 s][64 d] fp32 -> bf16
        const float* xrow = x + ((size_t)(b * Sn + s0 + r) * Dn + h * 64 + c0);
        unsigned int tmp[8];
        #pragma unroll
        for (int q4 = 0; q4 < 4; q4++) {
            float4 v = ((const float4*)xrow)[q4];
            tmp[2 * q4 + 0] = pk2bf(v.x, v.y);
            tmp[2 * q4 + 1] = pk2bf(v.z, v.w);
        }
        *(uint4*)&Xs[r * 72 + c0]     = ((uint4*)tmp)[0];
        *(uint4*)&Xs[r * 72 + c0 + 8] = ((uint4*)tmp)[1];
    }

    // A fragments: Wk^T / Wv^T rows e = w*16 + l (global, L2-hot)
    bf16x8 wk[2], wv[2];
    {
        const unsigned short* kp = wt_g + ((size_t)((1 * Hn + h) * 64 + w * 16 + l)) * 64 + quad * 8;
        const unsigned short* vp = wt_g + ((size_t)((2 * Hn + h) * 64 + w * 16 + l)) * 64 + quad * 8;
        uint4 a0 = *(const uint4*)kp;      uint4 a1 = *(const uint4*)(kp + 32);
        uint4 b0 = *(const uint4*)vp;      uint4 b1 = *(const uint4*)(vp + 32);
        wk[0] = *(bf16x8*)&a0; wk[1] = *(bf16x8*)&a1;
        wv[0] = *(bf16x8*)&b0; wv[1] = *(bf16x8*)&b1;
    }
    float4 bkv = *(const float4*)(bk + h * 64 + w * 16 + quad * 4);
    float4 bvv = *(const float4*)(bv + h * 64 + w * 16 + quad * 4);

    __syncthreads();

    // B fragments: X s-tiles
    bf16x8 xb[4][2];
    #pragma unroll
    for (int nt = 0; nt < 4; nt++)
        #pragma unroll
        for (int kc = 0; kc < 2; kc++)
            xb[nt][kc] = *(bf16x8*)&Xs[(nt * 16 + l) * 72 + kc * 32 + quad * 8];

    f32x4 ak[4], av[4];
    #pragma unroll
    for (int nt = 0; nt < 4; nt++) {
        ak[nt] = (f32x4){bkv.x * SQC, bkv.y * SQC, bkv.z * SQC, bkv.w * SQC};
        av[nt] = (f32x4){bvv.x, bvv.y, bvv.z, bvv.w};
    }
    #pragma unroll
    for (int nt = 0; nt < 4; nt++)
        #pragma unroll
        for (int kc = 0; kc < 2; kc++) {
            ak[nt] = __builtin_amdgcn_mfma_f32_16x16x32_bf16(wk[kc], xb[nt][kc], ak[nt], 0, 0, 0);
            av[nt] = __builtin_amdgcn_mfma_f32_16x16x32_bf16(wv[kc], xb[nt][kc], av[nt], 0, 0, 0);
        }

    // stage outputs
    #pragma unroll
    for (int nt = 0; nt < 4; nt++) {
        *(uint2*)&ObK[(nt * 16 + l) * 72 + w * 16 + quad * 4] =
            make_uint2(pk2bf(ak[nt][0], ak[nt][1]), pk2bf(ak[nt][2], ak[nt][3]));
        #pragma unroll
        for (int rr = 0; rr < 4; rr++)
            ObV[(w * 16 + quad * 4 + rr) * 72 + nt * 16 + l] = f2bf(av[nt][rr]);
    }
    __syncthreads();

    // coalesced b128 global stores
    {
        uint4 a = *(uint4*)&ObK[r * 72 + c0];
        uint4 bq4 = *(uint4*)&ObK[r * 72 + c0 + 8];
        unsigned short* dst = k_ws + (size_t)(bh * Sn + s0 + r) * 64 + c0;
        ((uint4*)dst)[0] = a;
        *(uint4*)(dst + 8) = bq4;
    }
    {
        uint4 a = *(uint4*)&ObV[r * 72 + c0];
        uint4 bq4 = *(uint4*)&ObV[r * 72 + c0 + 8];
        unsigned short* dst = vt_ws + (size_t)bh * 64 * Sn + (size_t)r * Sn + s0 + c0;
        ((uint4*)dst)[0] = a;
        *(uint4*)(dst + 8) = bq4;
    }
}

// ---------------------------------------------------------------------------
// Kernel 2 (attn): fused Q-projection + MFMA flash attention.
// 128 queries/block (32/wave). Prologue: Q = x.Wq + bq via 16 MFMAs/wave,
// LDS roundtrip to B-frag layout (per-wave region, no barrier).
// K-loop: block-staged K/V tiles; S^T = K.Q^T -> exp2 (no max: scores
// statically bounded, scale pre-folded) -> perm-packed P roundtrip ->
// O += P.V. XCD swizzle keeps each bh's K/V L2-resident.
// ---------------------------------------------------------------------------
__global__ __launch_bounds__(256) void attn_kernel(
    const float* __restrict__ x, const unsigned short* __restrict__ wt_g,
    const float* __restrict__ bq,
    const unsigned short* __restrict__ k_ws,
    const unsigned short* __restrict__ vt_ws,
    float* __restrict__ out)
{
    __shared__ unsigned short Ks[64 * 72];       // [key][dh]
    __shared__ unsigned short Vt[64 * 72];       // [dh][key]
    __shared__ unsigned short Pws[4 * 32 * 72];  // per-wave P / Q staging

    const int blk = blockIdx.x;    // 768 = 8 XCD * 12 bh * 8 qt
    const int xcd = blk & 7;
    const int idx = blk >> 3;      // 0..95
    const int bh  = xcd * 12 + (idx % 12);
    const int qt  = idx / 12;      // 0..7 (128-query tiles)
    const int t    = threadIdx.x;
    const int w    = t >> 6;
    const int lane = t & 63;
    const int l    = lane & 15;
    const int quad = lane >> 4;
    const int sr   = t >> 2;
    const int sc0  = (t & 3) * 16;

    const int b = bh / Hn, h = bh % Hn;
    const size_t base  = (size_t)bh * Sn * 64;   // k [bh][s][64]
    const size_t vbase = (size_t)bh * 64 * Sn;   // vt [bh][dh][S]

    unsigned short* Pw = Pws + w * 32 * 72;

    // ---- Q-projection prologue: 32 queries per wave ----
    bf16x8 qf[2][2];
    {
        // X as B-frag: lane l = query, k = kc*32 + quad*8 + j
        bf16x8 xq[2][2];
        #pragma unroll
        for (int st = 0; st < 2; st++) {
            const float* xp = x + ((size_t)(b * Sn + qt * 128 + w * 32 + st * 16 + l) * Dn
                                   + h * 64 + quad * 8);
            #pragma unroll
            for (int kc = 0; kc < 2; kc++) {
                float4 v0 = *(const float4*)(xp + kc * 32);
                float4 v1 = *(const float4*)(xp + kc * 32 + 4);
                unsigned int tmp[4] = {pk2bf(v0.x, v0.y), pk2bf(v0.z, v0.w),
                                       pk2bf(v1.x, v1.y), pk2bf(v1.z, v1.w)};
                xq[st][kc] = *(bf16x8*)tmp;
            }
        }
        // Wq^T A-frags per e-tile nt: row e = nt*16 + l (pre-scaled by SQC)
        #pragma unroll
        for (int nt = 0; nt < 4; nt++) {
            const unsigned short* wp = wt_g + ((size_t)((0 * Hn + h) * 64 + nt * 16 + l)) * 64 + quad * 8;
            uint4 a0 = *(const uint4*)wp;
            uint4 a1 = *(const uint4*)(wp + 32);
            bf16x8 wa0 = *(bf16x8*)&a0, wa1 = *(bf16x8*)&a1;
            float4 bqv = *(const float4*)(bq + h * 64 + nt * 16 + quad * 4);
            #pragma unroll
            for (int st = 0; st < 2; st++) {
                f32x4 acc = (f32x4){bqv.x * SQC, bqv.y * SQC, bqv.z * SQC, bqv.w * SQC};
                acc = __builtin_amdgcn_mfma_f32_16x16x32_bf16(wa0, xq[st][0], acc, 0, 0, 0);
                acc = __builtin_amdgcn_mfma_f32_16x16x32_bf16(wa1, xq[st][1], acc, 0, 0, 0);
                // C-layout: col = query = l, rows e = nt*16 + quad*4 + r
                *(uint2*)&Pw[(st * 16 + l) * 72 + nt * 16 + quad * 4] =
                    make_uint2(pk2bf(acc[0], acc[1]), pk2bf(acc[2], acc[3]));
            }
        }
        __asm__ volatile("s_waitcnt lgkmcnt(0)" ::: "memory");
        #pragma unroll
        for (int st = 0; st < 2; st++) {
            qf[st][0] = *(bf16x8*)&Pw[(st * 16 + l) * 72 + quad * 8];
            qf[st][1] = *(bf16x8*)&Pw[(st * 16 + l) * 72 + 32 + quad * 8];
        }
    }

    f32x4 Oa[2][4];
    #pragma unroll
    for (int st = 0; st < 2; st++)
        #pragma unroll
        for (int nt = 0; nt < 4; nt++) Oa[st][nt] = (f32x4){0.f, 0.f, 0.f, 0.f};
    float ps[2] = {0.f, 0.f};

    for (int kt = 0; kt < 16; kt++) {
        __syncthreads();   // drain prev-iter Ks/Vt readers
        {   // stage K tile [key][dh] and V^T tile [dh][key]
            const unsigned short* kp = k_ws + base + (size_t)(kt * 64 + sr) * 64 + sc0;
            uint4 ka = *(const uint4*)kp;
            uint4 kb = *(const uint4*)(kp + 8);
            const unsigned short* vp = vt_ws + vbase + (size_t)sr * Sn + kt * 64 + sc0;
            uint4 va = *(const uint4*)vp;
            uint4 vb = *(const uint4*)(vp + 8);
            *(uint4*)&Ks[sr * 72 + sc0]     = ka;
            *(uint4*)&Ks[sr * 72 + sc0 + 8] = kb;
            *(uint4*)&Vt[sr * 72 + sc0]     = va;
            *(uint4*)&Vt[sr * 72 + sc0 + 8] = vb;
        }
        __syncthreads();

        // S^T per key-strip nt: A = K rows, B = Q; then exp2 + packed P write
        #pragma unroll
        for (int nt = 0; nt < 4; nt++) {
            bf16x8 kf0 = *(bf16x8*)&Ks[(nt * 16 + l) * 72 + quad * 8];
            bf16x8 kf1 = *(bf16x8*)&Ks[(nt * 16 + l) * 72 + 32 + quad * 8];
            #pragma unroll
            for (int st = 0; st < 2; st++) {
                f32x4 s = (f32x4){0.f, 0.f, 0.f, 0.f};
                s = __builtin_amdgcn_mfma_f32_16x16x32_bf16(kf0, qf[st][0], s, 0, 0, 0);
                s = __builtin_amdgcn_mfma_f32_16x16x32_bf16(kf1, qf[st][1], s, 0, 0, 0);
                float p0 = exp2f(s[0]), p1 = exp2f(s[1]);
                float p2 = exp2f(s[2]), p3 = exp2f(s[3]);
                ps[st] += (p0 + p1) + (p2 + p3);
                *(uint2*)&Pw[(st * 16 + l) * 72 + nt * 16 + quad * 4] =
                    make_uint2(pk2bf(p0, p1), pk2bf(p2, p3));
            }
        }
        __asm__ volatile("s_waitcnt lgkmcnt(0)" ::: "memory");

        bf16x8 pf[2][2];
        #pragma unroll
        for (int st = 0; st < 2; st++) {
            pf[st][0] = *(bf16x8*)&Pw[(st * 16 + l) * 72 + quad * 8];
            pf[st][1] = *(bf16x8*)&Pw[(st * 16 + l) * 72 + 32 + quad * 8];
        }

        // O += P.V : B = V^T rows from LDS, shared across strips
        #pragma unroll
        for (int nt = 0; nt < 4; nt++) {
            bf16x8 vf0 = *(bf16x8*)&Vt[(nt * 16 + l) * 72 + quad * 8];
            bf16x8 vf1 = *(bf16x8*)&Vt[(nt * 16 + l) * 72 + 32 + quad * 8];
            #pragma unroll
            for (int st = 0; st < 2; st++) {
                Oa[st][nt] = __builtin_amdgcn_mfma_f32_16x16x32_bf16(pf[st][0], vf0, Oa[st][nt], 0, 0, 0);
                Oa[st][nt] = __builtin_amdgcn_mfma_f32_16x16x32_bf16(pf[st][1], vf1, Oa[st][nt], 0, 0, 0);
            }
        }
    }

    // fold partial sums across the 4 quads (keys), then fetch per-query inv
    #pragma unroll
    for (int st = 0; st < 2; st++) {
        ps[st] += __shfl_xor(ps[st], 16, 64);
        ps[st] += __shfl_xor(ps[st], 32, 64);
    }

    #pragma unroll
    for (int st = 0; st < 2; st++) {
        float inv[4];
        #pragma unroll
        for (int r = 0; r < 4; r++) inv[r] = 1.0f / __shfl(ps[st], quad * 4 + r, 64);
        #pragma unroll
        for (int nt = 0; nt < 4; nt++)
            #pragma unroll
            for (int r = 0; r < 4; r++) {
                int srow = qt * 128 + w * 32 + st * 16 + quad * 4 + r;
                out[(size_t)(b * Sn + srow) * Dn + h * 64 + nt * 16 + l] = Oa[st][nt][r] * inv[r];
            }
    }
}

// ---------------------------------------------------------------------------
extern "C" void kernel_launch(void* const* d_in, const int* in_sizes, int n_in,
                              void* d_out, int out_size, void* d_ws, size_t ws_size,
                              hipStream_t stream) {
    const float* x  = (const float*)d_in[0];
    const float* Wq = (const float*)d_in[1];
    const float* bq = (const float*)d_in[2];
    const float* Wk = (const float*)d_in[3];
    const float* bk = (const float*)d_in[4];
    const float* Wv = (const float*)d_in[5];
    const float* bv = (const float*)d_in[6];
    float* out = (float*)d_out;

    unsigned short* k_ws  = (unsigned short*)d_ws;
    unsigned short* vt_ws = k_ws + QKV_ELEMS;
    unsigned short* wt_g  = vt_ws + QKV_ELEMS;   // 36*64*64 bf16 = 288 KB

    hipLaunchKernelGGL(prep_kernel, dim3(3 * Hn), dim3(256), 0, stream,
                       Wq, Wk, Wv, wt_g);
    hipLaunchKernelGGL(proj_kernel, dim3(Bn * Hn * 16), dim3(256), 0, stream,
                       x, wt_g, bk, bv, k_ws, vt_ws);
    hipLaunchKernelGGL(attn_kernel, dim3(Bn * Hn * 8), dim3(256), 0, stream,
                       x, wt_g, bq, k_ws, vt_ws, out);
}